// Round 7
// baseline (408.217 us; speedup 1.0000x reference)
//
#include <hip/hip_runtime.h>

#define N_NODES 50000
#define N_EDGES 800000
#define LSTRIDE 68

typedef __bf16 bf16x8 __attribute__((ext_vector_type(8)));
typedef unsigned short ushort8 __attribute__((ext_vector_type(8)));
typedef unsigned short u16x4 __attribute__((ext_vector_type(4)));
typedef float f32x4 __attribute__((ext_vector_type(4)));

__device__ __forceinline__ unsigned short f2bf(float f) {
    unsigned u = __builtin_bit_cast(unsigned, f);
    u += 0x7fffu + ((u >> 16) & 1u);
    return (unsigned short)(u >> 16);
}
__device__ __forceinline__ float bf2f(unsigned short u) {
    return __builtin_bit_cast(float, (unsigned)u << 16);
}

__device__ __forceinline__ f32x4 shfl_xor4(f32x4 v, int m) {
    f32x4 r;
    r[0] = __shfl_xor(v[0], m); r[1] = __shfl_xor(v[1], m);
    r[2] = __shfl_xor(v[2], m); r[3] = __shfl_xor(v[3], m);
    return r;
}
__device__ __forceinline__ f32x4 sel4(bool p, f32x4 a, f32x4 b) {
    f32x4 r;
    r[0] = p ? a[0] : b[0]; r[1] = p ? a[1] : b[1];
    r[2] = p ? a[2] : b[2]; r[3] = p ? a[3] : b[3];
    return r;
}

// Permuted channel order (agg rows, x_bf, h1_bf):
//   pos(ch) = ch[3:2]<<4 | ch[5:4]<<2 | ch[1:0]
//
// [R1] scattered 64B data writes amplify L2 RMW (WRITE 53->78MB); tolerable.
// [R2] random reads inside per-node gather loops are latency-bound — keep
//      random access in flat kernels.
// [R3] nt-stores on scattered rows bypass L2 write-combine (77->177MB). Never.
// [R4] grid.sync() ~140us each on MI355X — cooperative multi-phase is dead.
//      Inter-dispatch gaps are SMALL (graph capture) — optimize kernel time.
// [R5] scattered global fp32 atomics to a 12.8MB target: ~64B DRAM txn each
//      (WRITE 194MB). Dead. (L2-resident int atomics are a different regime.)
// [R6] weight-preload prologue was NOT the node/gather cost (pretranspose
//      tied). Remaining redundancies: rank round-trip, returning-atomic
//      hist, agg global round-trip -> this round removes all three.

// Transposed bf16 weight blob layout (offsets in u16 elements):
//   lt1  [64 out][32 k]  @ 0       (c1 lin)
//   wt1a [64][64]        @ 2048    (c1 w1)
//   wt1b [64][64]        @ 6144    (c1 w2)
//   lt2  [64][32]        @ 10240   (c2 lin)
//   wt2a [64][64]        @ 12288   (c2 w1)
//   wt2b [64][64]        @ 16384   (c2 w2)
//   ht   [32 out][64 k]  @ 20480   (head)
#define WTB_ELEMS 22528

__global__ __launch_bounds__(256) void w_prep(
    const float* __restrict__ c1lw, const float* __restrict__ c1w1,
    const float* __restrict__ c1w2, const float* __restrict__ c2lw,
    const float* __restrict__ c2w1, const float* __restrict__ c2w2,
    const float* __restrict__ hw, unsigned short* __restrict__ wtb) {
    const int i = blockIdx.x * 256 + threadIdx.x;
    if (i >= WTB_ELEMS) return;
    float v;
    if (i < 2048)        { const int j = i;          v = c1lw[(j & 31) * 64 + (j >> 5)]; }
    else if (i < 6144)   { const int j = i - 2048;   v = c1w1[(j & 63) * 64 + (j >> 6)]; }
    else if (i < 10240)  { const int j = i - 6144;   v = c1w2[(j & 63) * 64 + (j >> 6)]; }
    else if (i < 12288)  { const int j = i - 10240;  v = c2lw[(j & 31) * 64 + (j >> 5)]; }
    else if (i < 16384)  { const int j = i - 12288;  v = c2w1[(j & 63) * 64 + (j >> 6)]; }
    else if (i < 20480)  { const int j = i - 16384;  v = c2w2[(j & 63) * 64 + (j >> 6)]; }
    else                 { const int j = i - 20480;  v = hw[(j & 63) * 32 + (j >> 6)]; }
    wtb[i] = f2bf(v);
}

// ======================= CSR build =======================
// histogram (NON-returning atomics — no rank) + x->bf16 permuted fused.
__global__ __launch_bounds__(256) void hist_xbf(
    const int* __restrict__ dstp, int* __restrict__ cnt,
    const float* __restrict__ x, unsigned short* __restrict__ xbf) {
    const int tid = blockIdx.x * blockDim.x + threadIdx.x;
    const int nthr = gridDim.x * blockDim.x;
    for (int e = tid; e < N_EDGES; e += nthr)
        atomicAdd(&cnt[dstp[e]], 1);
    for (int i = tid; i < N_NODES * 16; i += nthr) {
        const int n = i >> 4, b = i & 15;
        const float4 v = *(const float4*)(x + (size_t)n * 64 + b * 4);
        u16x4 o;
        o[0] = f2bf(v.x); o[1] = f2bf(v.y); o[2] = f2bf(v.z); o[3] = f2bf(v.w);
        *(u16x4*)(xbf + (size_t)n * 64 + (b & 3) * 16 + (b >> 2) * 4) = o;
    }
}

__global__ __launch_bounds__(256) void scan_p1(const int* __restrict__ cnt,
                                               int* __restrict__ bsum) {
    __shared__ int sm[256];
    const int t = threadIdx.x;
    const int idx = blockIdx.x * 256 + t;
    sm[t] = (idx < N_NODES) ? cnt[idx] : 0;
    __syncthreads();
    for (int off = 128; off > 0; off >>= 1) {
        if (t < off) sm[t] += sm[t + off];
        __syncthreads();
    }
    if (t == 0) bsum[blockIdx.x] = sm[0];
}

__global__ __launch_bounds__(256) void scan_p2(const int* __restrict__ bsum,
                                               int* __restrict__ bpre,
                                               int* __restrict__ offs) {
    __shared__ int sm[256];
    const int t = threadIdx.x;
    int v = bsum[t];
    sm[t] = v;
    __syncthreads();
    for (int off = 1; off < 256; off <<= 1) {
        int u = (t >= off) ? sm[t - off] : 0;
        __syncthreads();
        sm[t] += u;
        __syncthreads();
    }
    bpre[t] = sm[t] - v;
    if (t == 255) offs[N_NODES] = sm[255];
}

// per-tile scan -> offs AND a working copy for the atomic-pos scatter
__global__ __launch_bounds__(256) void scan_p3(const int* __restrict__ cnt,
                                               const int* __restrict__ bpre,
                                               int* __restrict__ offs,
                                               int* __restrict__ offs_work) {
    __shared__ int sm[256];
    const int t = threadIdx.x;
    const int idx = blockIdx.x * 256 + t;
    const int v = (idx < N_NODES) ? cnt[idx] : 0;
    sm[t] = v;
    __syncthreads();
    for (int off = 1; off < 256; off <<= 1) {
        int u = (t >= off) ? sm[t - off] : 0;
        __syncthreads();
        sm[t] += u;
        __syncthreads();
    }
    if (idx < N_NODES) {
        const int o = bpre[blockIdx.x] + sm[t] - v;
        offs[idx] = o;
        offs_work[idx] = o;
    }
}

// fallback-only index scatter (perm + ssrc) via atomic pos
__global__ __launch_bounds__(256) void csr_scatter_perm_srcs(
    const int* __restrict__ dstp, int* __restrict__ offs_work,
    const int* __restrict__ srcp,
    int* __restrict__ perm, int* __restrict__ ssrc) {
    for (int e = blockIdx.x * blockDim.x + threadIdx.x; e < N_EDGES;
         e += gridDim.x * blockDim.x) {
        const int pos = atomicAdd(&offs_work[dstp[e]], 1);
        perm[pos] = e;
        ssrc[pos] = srcp[e];
    }
}

// primary fused data scatter: seq ea read, scattered 64B bf16 row write
// (regular stores per R3), pos via one L2-resident int atomic (no rank).
__global__ __launch_bounds__(256) void csr_scatter_ea(
    const float* __restrict__ ea, const int* __restrict__ srcp,
    const int* __restrict__ dstp, int* __restrict__ offs_work,
    int* __restrict__ ssrc, unsigned short* __restrict__ ea_s) {
    const int e = blockIdx.x * blockDim.x + threadIdx.x;
    if (e >= N_EDGES) return;
    const int d = dstp[e];
    const int pos = atomicAdd(&offs_work[d], 1);
    ssrc[pos] = srcp[e];
    const float* er = ea + (size_t)e * 32;
    unsigned short* op = ea_s + (size_t)pos * 32;
#pragma unroll
    for (int sgm = 0; sgm < 4; ++sgm) {
        const float4 v0 = *(const float4*)(er + sgm * 8);
        const float4 v1 = *(const float4*)(er + sgm * 8 + 4);
        ushort8 u;
        u[0] = f2bf(v0.x); u[1] = f2bf(v0.y); u[2] = f2bf(v0.z); u[3] = f2bf(v0.w);
        u[4] = f2bf(v1.x); u[5] = f2bf(v1.y); u[6] = f2bf(v1.z); u[7] = f2bf(v1.w);
        *(ushort8*)(op + sgm * 8) = u;
    }
}

// ---------------------------------------------------------------------------
// FUSED conv1: one wave = one 16-node tile. Phase 1: per-node gather (proven
// R1 body) writing agg rows into the wave's private LDS slice. Phase 2: the
// proven node-MLP body with ar -> LDS. agg never exists globally.
// ---------------------------------------------------------------------------
__global__ __launch_bounds__(256) void gine_conv1(
    const unsigned short* __restrict__ xbf,   // [N,64] bf16 permuted
    const float* __restrict__ xin,            // [N,64] fp32
    const unsigned short* __restrict__ eas,   // [E,32] bf16 dst-sorted
    const int*   __restrict__ ssrc,
    const int*   __restrict__ offs,
    const unsigned short* __restrict__ lt,    // [64][32] bf16 (lin^T)
    const float* __restrict__ linB,
    const unsigned short* __restrict__ wt1, const float* __restrict__ b1,
    const unsigned short* __restrict__ wt2, const float* __restrict__ b2,
    unsigned short* __restrict__ hbf)          // [N,64] bf16 permuted
{
    __shared__ float lds[4][16 * LSTRIDE];
    const int lane = threadIdx.x & 63;
    const int c = lane & 15, q = lane >> 4;
    float* L = lds[threadIdx.x >> 6];

    const int gwave  = (blockIdx.x * blockDim.x + threadIdx.x) >> 6;
    const int nwaves = (gridDim.x * blockDim.x) >> 6;

    bf16x8 wf[4];
#pragma unroll
    for (int mt = 0; mt < 4; ++mt)
        wf[mt] = __builtin_bit_cast(bf16x8,
            *(const ushort8*)(lt + (mt * 16 + c) * 32 + q * 8));
    f32x4 biasv[4];
#pragma unroll
    for (int mt = 0; mt < 4; ++mt)
        biasv[mt] = *(const f32x4*)(linB + mt * 16 + q * 4);

    bf16x8 a1[4][2], a2[4][2];
#pragma unroll
    for (int mt = 0; mt < 4; ++mt)
#pragma unroll
        for (int ks = 0; ks < 2; ++ks) {
            a1[mt][ks] = __builtin_bit_cast(bf16x8,
                *(const ushort8*)(wt1 + (mt * 16 + c) * 64 + ks * 32 + q * 8));
            a2[mt][ks] = __builtin_bit_cast(bf16x8,
                *(const ushort8*)(wt2 + (mt * 16 + c) * 64 + ks * 32 + q * 8));
        }
    f32x4 b1v[4], b2v[4];
#pragma unroll
    for (int mt = 0; mt < 4; ++mt) {
        b1v[mt] = *(const f32x4*)(b1 + mt * 16 + q * 4);
        b2v[mt] = *(const f32x4*)(b2 + mt * 16 + q * 4);
    }

    const int ntiles = N_NODES / 16;
    for (int tile = gwave; tile < ntiles; tile += nwaves) {
        const int n0 = tile * 16;
        const int ob = (lane < 17) ? offs[n0 + lane] : 0;

        // -------- phase 1: gather agg rows for 16 nodes into LDS --------
        for (int j = 0; j < 16; ++j) {
            const int start = __shfl(ob, j);
            const int end   = __shfl(ob, j + 1);
            const int pidx = (start + lane < end) ? (start + lane)
                                                  : ((end > start) ? end - 1 : 0);
            const int sl = ssrc[pidx];

            f32x4 s0 = {0.f,0.f,0.f,0.f}, s1 = {0.f,0.f,0.f,0.f};
            f32x4 s2 = {0.f,0.f,0.f,0.f}, s3 = {0.f,0.f,0.f,0.f};

            int t = 0;
            for (int base = start; base < end; base += 16, ++t) {
                const int eidx = base + c;
                const bool valid = eidx < end;
                const int ecl = valid ? eidx : end - 1;

                const bf16x8 bf = __builtin_bit_cast(bf16x8,
                    *(const ushort8*)(eas + (size_t)ecl * 32 + q * 8));

                int s;
                if (t < 4) s = __shfl(sl, (t << 4) + c);
                else       s = ssrc[ecl];

                f32x4 acc[4];
                acc[0] = __builtin_amdgcn_mfma_f32_16x16x32_bf16(wf[0], bf, biasv[0], 0, 0, 0);
                acc[1] = __builtin_amdgcn_mfma_f32_16x16x32_bf16(wf[1], bf, biasv[1], 0, 0, 0);
                acc[2] = __builtin_amdgcn_mfma_f32_16x16x32_bf16(wf[2], bf, biasv[2], 0, 0, 0);
                acc[3] = __builtin_amdgcn_mfma_f32_16x16x32_bf16(wf[3], bf, biasv[3], 0, 0, 0);

                const unsigned short* xr = xbf + (size_t)s * 64 + q * 16;
                const ushort8 xa = *(const ushort8*)xr;
                const ushort8 xb = *(const ushort8*)(xr + 8);

                const float NEG = -3.0e38f;
#pragma unroll
                for (int r = 0; r < 4; ++r) {
                    s0[r] += fmaxf((valid ? bf2f(xa[r])     : NEG) + acc[0][r], 0.f);
                    s1[r] += fmaxf((valid ? bf2f(xa[4 + r]) : NEG) + acc[1][r], 0.f);
                    s2[r] += fmaxf((valid ? bf2f(xb[r])     : NEG) + acc[2][r], 0.f);
                    s3[r] += fmaxf((valid ? bf2f(xb[4 + r]) : NEG) + acc[3][r], 0.f);
                }
            }

            f32x4 t0 = sel4((c & 8) != 0, s2, s0) + shfl_xor4(sel4((c & 8) != 0, s0, s2), 8);
            f32x4 t1 = sel4((c & 8) != 0, s3, s1) + shfl_xor4(sel4((c & 8) != 0, s1, s3), 8);
            f32x4 u = sel4((c & 4) != 0, t1, t0) + shfl_xor4(sel4((c & 4) != 0, t0, t1), 4);
            float v0 = ((c & 2) ? u[2] : u[0]) + __shfl_xor((c & 2) ? u[0] : u[2], 2);
            float v1 = ((c & 2) ? u[3] : u[1]) + __shfl_xor((c & 2) ? u[1] : u[3], 2);
            float w = ((c & 1) ? v1 : v0) + __shfl_xor((c & 1) ? v0 : v1, 1);

            L[j * LSTRIDE + lane] = w;   // agg row j, permuted channel = lane
        }
        asm volatile("s_waitcnt lgkmcnt(0)" ::: "memory");

        // -------- phase 2: node MLP (proven body, ar -> LDS) --------
        const float* xr = xin + (size_t)(n0 + c) * 64;
        const float* arL = L + c * LSTRIDE;

        bf16x8 hb[2];
#pragma unroll
        for (int ks = 0; ks < 2; ++ks) {
            const int o = ks * 32 + q * 8;
            const int b0 = o >> 2, b1i = b0 + 1;
            const float4 xa = *(const float4*)(xr + o);
            const float4 xb = *(const float4*)(xr + o + 4);
            const f32x4 aa = *(const f32x4*)(arL + ((b0 & 3) * 16 + (b0 >> 2) * 4));
            const f32x4 ab = *(const f32x4*)(arL + ((b1i & 3) * 16 + (b1i >> 2) * 4));
            ushort8 u;
            u[0] = f2bf(xa.x + aa[0]); u[1] = f2bf(xa.y + aa[1]);
            u[2] = f2bf(xa.z + aa[2]); u[3] = f2bf(xa.w + aa[3]);
            u[4] = f2bf(xb.x + ab[0]); u[5] = f2bf(xb.y + ab[1]);
            u[6] = f2bf(xb.z + ab[2]); u[7] = f2bf(xb.w + ab[3]);
            hb[ks] = __builtin_bit_cast(bf16x8, u);
        }
        asm volatile("s_waitcnt lgkmcnt(0)" ::: "memory");

        f32x4 acc[4];
#pragma unroll
        for (int mt = 0; mt < 4; ++mt) {
            acc[mt] = __builtin_amdgcn_mfma_f32_16x16x32_bf16(
                a1[mt][0], hb[0], (f32x4){0.f, 0.f, 0.f, 0.f}, 0, 0, 0);
            acc[mt] = __builtin_amdgcn_mfma_f32_16x16x32_bf16(
                a1[mt][1], hb[1], acc[mt], 0, 0, 0);
        }

#pragma unroll
        for (int mt = 0; mt < 4; ++mt) {
            f32x4 t;
#pragma unroll
            for (int r = 0; r < 4; ++r) t[r] = fmaxf(acc[mt][r] + b1v[mt][r], 0.f);
            *(f32x4*)(L + c * LSTRIDE + mt * 16 + q * 4) = t;
        }
        asm volatile("s_waitcnt lgkmcnt(0)" ::: "memory");

        bf16x8 tb[2];
#pragma unroll
        for (int ks = 0; ks < 2; ++ks) {
            const f32x4 lo = *(const f32x4*)(L + c * LSTRIDE + ks * 32 + q * 8);
            const f32x4 hi = *(const f32x4*)(L + c * LSTRIDE + ks * 32 + q * 8 + 4);
            ushort8 u;
            u[0] = f2bf(lo[0]); u[1] = f2bf(lo[1]); u[2] = f2bf(lo[2]); u[3] = f2bf(lo[3]);
            u[4] = f2bf(hi[0]); u[5] = f2bf(hi[1]); u[6] = f2bf(hi[2]); u[7] = f2bf(hi[3]);
            tb[ks] = __builtin_bit_cast(bf16x8, u);
        }
        asm volatile("s_waitcnt lgkmcnt(0)" ::: "memory");

#pragma unroll
        for (int mt = 0; mt < 4; ++mt) {
            acc[mt] = __builtin_amdgcn_mfma_f32_16x16x32_bf16(
                a2[mt][0], tb[0], (f32x4){0.f, 0.f, 0.f, 0.f}, 0, 0, 0);
            acc[mt] = __builtin_amdgcn_mfma_f32_16x16x32_bf16(
                a2[mt][1], tb[1], acc[mt], 0, 0, 0);
        }

        unsigned short* hr = hbf + (size_t)(n0 + c) * 64 + q * 16;
        ushort8 lo8, hi8;
#pragma unroll
        for (int r = 0; r < 4; ++r) {
            lo8[r]     = f2bf(fmaxf(acc[0][r] + b2v[0][r], 0.f));
            lo8[4 + r] = f2bf(fmaxf(acc[1][r] + b2v[1][r], 0.f));
            hi8[r]     = f2bf(fmaxf(acc[2][r] + b2v[2][r], 0.f));
            hi8[4 + r] = f2bf(fmaxf(acc[3][r] + b2v[3][r], 0.f));
        }
        *(ushort8*)hr = lo8;
        *(ushort8*)(hr + 8) = hi8;
    }
}

// ---------------------------------------------------------------------------
// FUSED conv2 + head: gather reads hbf; MLP+head body with ar -> LDS.
// ---------------------------------------------------------------------------
__global__ __launch_bounds__(256) void gine_conv2_head(
    const unsigned short* __restrict__ hbfin, // [N,64] bf16 permuted (h1)
    const unsigned short* __restrict__ eas,
    const int*   __restrict__ ssrc,
    const int*   __restrict__ offs,
    const unsigned short* __restrict__ lt,    // [64][32] bf16 (c2 lin^T)
    const float* __restrict__ linB,
    const unsigned short* __restrict__ wt1, const float* __restrict__ b1,
    const unsigned short* __restrict__ wt2, const float* __restrict__ b2,
    const unsigned short* __restrict__ ht,   // [32][64] bf16 (head^T)
    const float* __restrict__ hbp,
    float* __restrict__ outp)
{
    __shared__ float lds[4][16 * LSTRIDE];
    const int lane = threadIdx.x & 63;
    const int c = lane & 15, q = lane >> 4;
    float* L = lds[threadIdx.x >> 6];

    const int gwave  = (blockIdx.x * blockDim.x + threadIdx.x) >> 6;
    const int nwaves = (gridDim.x * blockDim.x) >> 6;

    bf16x8 wf[4];
#pragma unroll
    for (int mt = 0; mt < 4; ++mt)
        wf[mt] = __builtin_bit_cast(bf16x8,
            *(const ushort8*)(lt + (mt * 16 + c) * 32 + q * 8));
    f32x4 biasv[4];
#pragma unroll
    for (int mt = 0; mt < 4; ++mt)
        biasv[mt] = *(const f32x4*)(linB + mt * 16 + q * 4);

    bf16x8 a1[4][2], a2[4][2], a3[2][2];
#pragma unroll
    for (int mt = 0; mt < 4; ++mt)
#pragma unroll
        for (int ks = 0; ks < 2; ++ks) {
            a1[mt][ks] = __builtin_bit_cast(bf16x8,
                *(const ushort8*)(wt1 + (mt * 16 + c) * 64 + ks * 32 + q * 8));
            a2[mt][ks] = __builtin_bit_cast(bf16x8,
                *(const ushort8*)(wt2 + (mt * 16 + c) * 64 + ks * 32 + q * 8));
        }
#pragma unroll
    for (int mt = 0; mt < 2; ++mt)
#pragma unroll
        for (int ks = 0; ks < 2; ++ks)
            a3[mt][ks] = __builtin_bit_cast(bf16x8,
                *(const ushort8*)(ht + (mt * 16 + c) * 64 + ks * 32 + q * 8));
    f32x4 b1v[4], b2v[4], hbv[2];
#pragma unroll
    for (int mt = 0; mt < 4; ++mt) {
        b1v[mt] = *(const f32x4*)(b1 + mt * 16 + q * 4);
        b2v[mt] = *(const f32x4*)(b2 + mt * 16 + q * 4);
    }
#pragma unroll
    for (int mt = 0; mt < 2; ++mt)
        hbv[mt] = *(const f32x4*)(hbp + mt * 16 + q * 4);

    const int ntiles = N_NODES / 16;
    for (int tile = gwave; tile < ntiles; tile += nwaves) {
        const int n0 = tile * 16;
        const int ob = (lane < 17) ? offs[n0 + lane] : 0;

        // -------- phase 1: gather (source features = h1) --------
        for (int j = 0; j < 16; ++j) {
            const int start = __shfl(ob, j);
            const int end   = __shfl(ob, j + 1);
            const int pidx = (start + lane < end) ? (start + lane)
                                                  : ((end > start) ? end - 1 : 0);
            const int sl = ssrc[pidx];

            f32x4 s0 = {0.f,0.f,0.f,0.f}, s1 = {0.f,0.f,0.f,0.f};
            f32x4 s2 = {0.f,0.f,0.f,0.f}, s3 = {0.f,0.f,0.f,0.f};

            int t = 0;
            for (int base = start; base < end; base += 16, ++t) {
                const int eidx = base + c;
                const bool valid = eidx < end;
                const int ecl = valid ? eidx : end - 1;

                const bf16x8 bf = __builtin_bit_cast(bf16x8,
                    *(const ushort8*)(eas + (size_t)ecl * 32 + q * 8));

                int s;
                if (t < 4) s = __shfl(sl, (t << 4) + c);
                else       s = ssrc[ecl];

                f32x4 acc[4];
                acc[0] = __builtin_amdgcn_mfma_f32_16x16x32_bf16(wf[0], bf, biasv[0], 0, 0, 0);
                acc[1] = __builtin_amdgcn_mfma_f32_16x16x32_bf16(wf[1], bf, biasv[1], 0, 0, 0);
                acc[2] = __builtin_amdgcn_mfma_f32_16x16x32_bf16(wf[2], bf, biasv[2], 0, 0, 0);
                acc[3] = __builtin_amdgcn_mfma_f32_16x16x32_bf16(wf[3], bf, biasv[3], 0, 0, 0);

                const unsigned short* xr = hbfin + (size_t)s * 64 + q * 16;
                const ushort8 xa = *(const ushort8*)xr;
                const ushort8 xb = *(const ushort8*)(xr + 8);

                const float NEG = -3.0e38f;
#pragma unroll
                for (int r = 0; r < 4; ++r) {
                    s0[r] += fmaxf((valid ? bf2f(xa[r])     : NEG) + acc[0][r], 0.f);
                    s1[r] += fmaxf((valid ? bf2f(xa[4 + r]) : NEG) + acc[1][r], 0.f);
                    s2[r] += fmaxf((valid ? bf2f(xb[r])     : NEG) + acc[2][r], 0.f);
                    s3[r] += fmaxf((valid ? bf2f(xb[4 + r]) : NEG) + acc[3][r], 0.f);
                }
            }

            f32x4 t0 = sel4((c & 8) != 0, s2, s0) + shfl_xor4(sel4((c & 8) != 0, s0, s2), 8);
            f32x4 t1 = sel4((c & 8) != 0, s3, s1) + shfl_xor4(sel4((c & 8) != 0, s1, s3), 8);
            f32x4 u = sel4((c & 4) != 0, t1, t0) + shfl_xor4(sel4((c & 4) != 0, t0, t1), 4);
            float v0 = ((c & 2) ? u[2] : u[0]) + __shfl_xor((c & 2) ? u[0] : u[2], 2);
            float v1 = ((c & 2) ? u[3] : u[1]) + __shfl_xor((c & 2) ? u[1] : u[3], 2);
            float w = ((c & 1) ? v1 : v0) + __shfl_xor((c & 1) ? v0 : v1, 1);

            L[j * LSTRIDE + lane] = w;
        }
        asm volatile("s_waitcnt lgkmcnt(0)" ::: "memory");

        // -------- phase 2: node MLP + head (ar -> LDS) --------
        const unsigned short* xr = hbfin + (size_t)(n0 + c) * 64;
        const float* arL = L + c * LSTRIDE;

        bf16x8 hb[2];
#pragma unroll
        for (int ks = 0; ks < 2; ++ks) {
            const int o = ks * 32 + q * 8;
            const int b0 = o >> 2, b1i = b0 + 1;
            const int pb0 = (b0 & 3) * 16 + (b0 >> 2) * 4;
            const int pb1 = (b1i & 3) * 16 + (b1i >> 2) * 4;
            const u16x4 xa4 = *(const u16x4*)(xr + pb0);
            const u16x4 xb4 = *(const u16x4*)(xr + pb1);
            const f32x4 aa = *(const f32x4*)(arL + pb0);
            const f32x4 ab = *(const f32x4*)(arL + pb1);
            ushort8 u;
#pragma unroll
            for (int i = 0; i < 4; ++i) {
                u[i]     = f2bf(bf2f(xa4[i]) + aa[i]);
                u[4 + i] = f2bf(bf2f(xb4[i]) + ab[i]);
            }
            hb[ks] = __builtin_bit_cast(bf16x8, u);
        }
        asm volatile("s_waitcnt lgkmcnt(0)" ::: "memory");

        f32x4 acc[4];
#pragma unroll
        for (int mt = 0; mt < 4; ++mt) {
            acc[mt] = __builtin_amdgcn_mfma_f32_16x16x32_bf16(
                a1[mt][0], hb[0], (f32x4){0.f, 0.f, 0.f, 0.f}, 0, 0, 0);
            acc[mt] = __builtin_amdgcn_mfma_f32_16x16x32_bf16(
                a1[mt][1], hb[1], acc[mt], 0, 0, 0);
        }

#pragma unroll
        for (int mt = 0; mt < 4; ++mt) {
            f32x4 t;
#pragma unroll
            for (int r = 0; r < 4; ++r) t[r] = fmaxf(acc[mt][r] + b1v[mt][r], 0.f);
            *(f32x4*)(L + c * LSTRIDE + mt * 16 + q * 4) = t;
        }
        asm volatile("s_waitcnt lgkmcnt(0)" ::: "memory");

        bf16x8 tb[2];
#pragma unroll
        for (int ks = 0; ks < 2; ++ks) {
            const f32x4 lo = *(const f32x4*)(L + c * LSTRIDE + ks * 32 + q * 8);
            const f32x4 hi = *(const f32x4*)(L + c * LSTRIDE + ks * 32 + q * 8 + 4);
            ushort8 u;
            u[0] = f2bf(lo[0]); u[1] = f2bf(lo[1]); u[2] = f2bf(lo[2]); u[3] = f2bf(lo[3]);
            u[4] = f2bf(hi[0]); u[5] = f2bf(hi[1]); u[6] = f2bf(hi[2]); u[7] = f2bf(hi[3]);
            tb[ks] = __builtin_bit_cast(bf16x8, u);
        }
        asm volatile("s_waitcnt lgkmcnt(0)" ::: "memory");

#pragma unroll
        for (int mt = 0; mt < 4; ++mt) {
            acc[mt] = __builtin_amdgcn_mfma_f32_16x16x32_bf16(
                a2[mt][0], tb[0], (f32x4){0.f, 0.f, 0.f, 0.f}, 0, 0, 0);
            acc[mt] = __builtin_amdgcn_mfma_f32_16x16x32_bf16(
                a2[mt][1], tb[1], acc[mt], 0, 0, 0);
        }

#pragma unroll
        for (int mt = 0; mt < 4; ++mt) {
            f32x4 t;
#pragma unroll
            for (int r = 0; r < 4; ++r) t[r] = fmaxf(acc[mt][r] + b2v[mt][r], 0.f);
            *(f32x4*)(L + c * LSTRIDE + mt * 16 + q * 4) = t;
        }
        asm volatile("s_waitcnt lgkmcnt(0)" ::: "memory");

        bf16x8 ub[2];
#pragma unroll
        for (int ks = 0; ks < 2; ++ks) {
            const f32x4 lo = *(const f32x4*)(L + c * LSTRIDE + ks * 32 + q * 8);
            const f32x4 hi = *(const f32x4*)(L + c * LSTRIDE + ks * 32 + q * 8 + 4);
            ushort8 u;
            u[0] = f2bf(lo[0]); u[1] = f2bf(lo[1]); u[2] = f2bf(lo[2]); u[3] = f2bf(lo[3]);
            u[4] = f2bf(hi[0]); u[5] = f2bf(hi[1]); u[6] = f2bf(hi[2]); u[7] = f2bf(hi[3]);
            ub[ks] = __builtin_bit_cast(bf16x8, u);
        }
        asm volatile("s_waitcnt lgkmcnt(0)" ::: "memory");

        f32x4 acc3[2];
#pragma unroll
        for (int mt = 0; mt < 2; ++mt) {
            acc3[mt] = __builtin_amdgcn_mfma_f32_16x16x32_bf16(
                a3[mt][0], ub[0], (f32x4){0.f, 0.f, 0.f, 0.f}, 0, 0, 0);
            acc3[mt] = __builtin_amdgcn_mfma_f32_16x16x32_bf16(
                a3[mt][1], ub[1], acc3[mt], 0, 0, 0);
        }

        float* outr = outp + (size_t)(n0 + c) * 32;
#pragma unroll
        for (int mt = 0; mt < 2; ++mt) {
            f32x4 u;
#pragma unroll
            for (int r = 0; r < 4; ++r) u[r] = acc3[mt][r] + hbv[mt][r];
            *(f32x4*)(outr + mt * 16 + q * 4) = u;
        }
    }
}

// ======================= fallback kernels (small ws) =======================

__global__ __launch_bounds__(256) void gine_gather_fb(
    const unsigned short* __restrict__ xbf, const float* __restrict__ ea,
    const int* __restrict__ perm, const int* __restrict__ ssrc,
    const int* __restrict__ offs, const unsigned short* __restrict__ lt,
    const float* __restrict__ linB, float* __restrict__ agg)
{
    const int lane = threadIdx.x & 63;
    const int gwave  = (blockIdx.x * blockDim.x + threadIdx.x) >> 6;
    const int nwaves = (gridDim.x * blockDim.x) >> 6;
    const int c = lane & 15;
    const int q = lane >> 4;

    bf16x8 wf[4];
#pragma unroll
    for (int mt = 0; mt < 4; ++mt)
        wf[mt] = __builtin_bit_cast(bf16x8,
            *(const ushort8*)(lt + (mt * 16 + c) * 32 + q * 8));
    f32x4 biasv[4];
#pragma unroll
    for (int mt = 0; mt < 4; ++mt)
        biasv[mt] = *(const f32x4*)(linB + mt * 16 + q * 4);

    for (int n = gwave; n < N_NODES; n += nwaves) {
        const int start = offs[n];
        const int end   = offs[n + 1];
        const int pidx = (start + lane < end) ? (start + lane)
                                              : ((end > start) ? end - 1 : 0);
        const int sl = ssrc[pidx];

        f32x4 s0 = {0.f,0.f,0.f,0.f}, s1 = {0.f,0.f,0.f,0.f};
        f32x4 s2 = {0.f,0.f,0.f,0.f}, s3 = {0.f,0.f,0.f,0.f};

        int t = 0;
        for (int base = start; base < end; base += 16, ++t) {
            const int eidx = base + c;
            const bool valid = eidx < end;
            const int ecl = valid ? eidx : end - 1;

            const int e = perm[ecl];
            const float* ap = ea + (size_t)e * 32 + q * 8;
            const float4 a0 = *(const float4*)ap;
            const float4 a1 = *(const float4*)(ap + 4);
            ushort8 ub;
            ub[0] = f2bf(a0.x); ub[1] = f2bf(a0.y); ub[2] = f2bf(a0.z); ub[3] = f2bf(a0.w);
            ub[4] = f2bf(a1.x); ub[5] = f2bf(a1.y); ub[6] = f2bf(a1.z); ub[7] = f2bf(a1.w);
            const bf16x8 bf = __builtin_bit_cast(bf16x8, ub);

            int s;
            if (t < 4) s = __shfl(sl, (t << 4) + c);
            else       s = ssrc[ecl];

            f32x4 acc[4];
            acc[0] = __builtin_amdgcn_mfma_f32_16x16x32_bf16(wf[0], bf, biasv[0], 0, 0, 0);
            acc[1] = __builtin_amdgcn_mfma_f32_16x16x32_bf16(wf[1], bf, biasv[1], 0, 0, 0);
            acc[2] = __builtin_amdgcn_mfma_f32_16x16x32_bf16(wf[2], bf, biasv[2], 0, 0, 0);
            acc[3] = __builtin_amdgcn_mfma_f32_16x16x32_bf16(wf[3], bf, biasv[3], 0, 0, 0);

            const unsigned short* xr = xbf + (size_t)s * 64 + q * 16;
            const ushort8 xa = *(const ushort8*)xr;
            const ushort8 xb = *(const ushort8*)(xr + 8);

            const float NEG = -3.0e38f;
#pragma unroll
            for (int r = 0; r < 4; ++r) {
                s0[r] += fmaxf((valid ? bf2f(xa[r])     : NEG) + acc[0][r], 0.f);
                s1[r] += fmaxf((valid ? bf2f(xa[4 + r]) : NEG) + acc[1][r], 0.f);
                s2[r] += fmaxf((valid ? bf2f(xb[r])     : NEG) + acc[2][r], 0.f);
                s3[r] += fmaxf((valid ? bf2f(xb[4 + r]) : NEG) + acc[3][r], 0.f);
            }
        }

        f32x4 t0 = sel4((c & 8) != 0, s2, s0) + shfl_xor4(sel4((c & 8) != 0, s0, s2), 8);
        f32x4 t1 = sel4((c & 8) != 0, s3, s1) + shfl_xor4(sel4((c & 8) != 0, s1, s3), 8);
        f32x4 u = sel4((c & 4) != 0, t1, t0) + shfl_xor4(sel4((c & 4) != 0, t0, t1), 4);
        float v0 = ((c & 2) ? u[2] : u[0]) + __shfl_xor((c & 2) ? u[0] : u[2], 2);
        float v1 = ((c & 2) ? u[3] : u[1]) + __shfl_xor((c & 2) ? u[1] : u[3], 2);
        float w = ((c & 1) ? v1 : v0) + __shfl_xor((c & 1) ? v0 : v1, 1);

        agg[(size_t)n * 64 + lane] = w;
    }
}

__global__ __launch_bounds__(256) void gine_node_mfma(
    const float* __restrict__ xin, const float* __restrict__ agg,
    const unsigned short* __restrict__ wt1, const float* __restrict__ b1,
    const unsigned short* __restrict__ wt2, const float* __restrict__ b2,
    unsigned short* __restrict__ hbf)
{
    __shared__ float lds[4][16 * LSTRIDE];
    const int lane = threadIdx.x & 63;
    const int c = lane & 15, q = lane >> 4;
    float* L = lds[threadIdx.x >> 6];

    const int gwave  = (blockIdx.x * blockDim.x + threadIdx.x) >> 6;
    const int nwaves = (gridDim.x * blockDim.x) >> 6;

    bf16x8 a1[4][2], a2[4][2];
#pragma unroll
    for (int mt = 0; mt < 4; ++mt)
#pragma unroll
        for (int ks = 0; ks < 2; ++ks) {
            a1[mt][ks] = __builtin_bit_cast(bf16x8,
                *(const ushort8*)(wt1 + (mt * 16 + c) * 64 + ks * 32 + q * 8));
            a2[mt][ks] = __builtin_bit_cast(bf16x8,
                *(const ushort8*)(wt2 + (mt * 16 + c) * 64 + ks * 32 + q * 8));
        }
    f32x4 b1v[4], b2v[4];
#pragma unroll
    for (int mt = 0; mt < 4; ++mt) {
        b1v[mt] = *(const f32x4*)(b1 + mt * 16 + q * 4);
        b2v[mt] = *(const f32x4*)(b2 + mt * 16 + q * 4);
    }

    const int ntiles = N_NODES / 16;
    for (int tile = gwave; tile < ntiles; tile += nwaves) {
        const int n0 = tile * 16;
        const float* xr = xin + (size_t)(n0 + c) * 64;
        const float* ar = agg + (size_t)(n0 + c) * 64;

        bf16x8 hb[2];
#pragma unroll
        for (int ks = 0; ks < 2; ++ks) {
            const int o = ks * 32 + q * 8;
            const int b0 = o >> 2, b1i = b0 + 1;
            const float4 xa = *(const float4*)(xr + o);
            const float4 xb = *(const float4*)(xr + o + 4);
            const float4 aa = *(const float4*)(ar + ((b0 & 3) * 16 + (b0 >> 2) * 4));
            const float4 ab = *(const float4*)(ar + ((b1i & 3) * 16 + (b1i >> 2) * 4));
            ushort8 u;
            u[0] = f2bf(xa.x + aa.x); u[1] = f2bf(xa.y + aa.y);
            u[2] = f2bf(xa.z + aa.z); u[3] = f2bf(xa.w + aa.w);
            u[4] = f2bf(xb.x + ab.x); u[5] = f2bf(xb.y + ab.y);
            u[6] = f2bf(xb.z + ab.z); u[7] = f2bf(xb.w + ab.w);
            hb[ks] = __builtin_bit_cast(bf16x8, u);
        }

        f32x4 acc[4];
#pragma unroll
        for (int mt = 0; mt < 4; ++mt) {
            acc[mt] = __builtin_amdgcn_mfma_f32_16x16x32_bf16(
                a1[mt][0], hb[0], (f32x4){0.f, 0.f, 0.f, 0.f}, 0, 0, 0);
            acc[mt] = __builtin_amdgcn_mfma_f32_16x16x32_bf16(
                a1[mt][1], hb[1], acc[mt], 0, 0, 0);
        }

#pragma unroll
        for (int mt = 0; mt < 4; ++mt) {
            f32x4 t;
#pragma unroll
            for (int r = 0; r < 4; ++r) t[r] = fmaxf(acc[mt][r] + b1v[mt][r], 0.f);
            *(f32x4*)(L + c * LSTRIDE + mt * 16 + q * 4) = t;
        }
        asm volatile("s_waitcnt lgkmcnt(0)" ::: "memory");

        bf16x8 tb[2];
#pragma unroll
        for (int ks = 0; ks < 2; ++ks) {
            const f32x4 lo = *(const f32x4*)(L + c * LSTRIDE + ks * 32 + q * 8);
            const f32x4 hi = *(const f32x4*)(L + c * LSTRIDE + ks * 32 + q * 8 + 4);
            ushort8 u;
            u[0] = f2bf(lo[0]); u[1] = f2bf(lo[1]); u[2] = f2bf(lo[2]); u[3] = f2bf(lo[3]);
            u[4] = f2bf(hi[0]); u[5] = f2bf(hi[1]); u[6] = f2bf(hi[2]); u[7] = f2bf(hi[3]);
            tb[ks] = __builtin_bit_cast(bf16x8, u);
        }
        asm volatile("s_waitcnt lgkmcnt(0)" ::: "memory");

#pragma unroll
        for (int mt = 0; mt < 4; ++mt) {
            acc[mt] = __builtin_amdgcn_mfma_f32_16x16x32_bf16(
                a2[mt][0], tb[0], (f32x4){0.f, 0.f, 0.f, 0.f}, 0, 0, 0);
            acc[mt] = __builtin_amdgcn_mfma_f32_16x16x32_bf16(
                a2[mt][1], tb[1], acc[mt], 0, 0, 0);
        }

        unsigned short* hr = hbf + (size_t)(n0 + c) * 64 + q * 16;
        ushort8 lo8, hi8;
#pragma unroll
        for (int r = 0; r < 4; ++r) {
            lo8[r]     = f2bf(fmaxf(acc[0][r] + b2v[0][r], 0.f));
            lo8[4 + r] = f2bf(fmaxf(acc[1][r] + b2v[1][r], 0.f));
            hi8[r]     = f2bf(fmaxf(acc[2][r] + b2v[2][r], 0.f));
            hi8[4 + r] = f2bf(fmaxf(acc[3][r] + b2v[3][r], 0.f));
        }
        *(ushort8*)hr = lo8;
        *(ushort8*)(hr + 8) = hi8;
    }
}

__global__ __launch_bounds__(256) void gine_node_head_mfma(
    const unsigned short* __restrict__ xbf, const float* __restrict__ agg,
    const unsigned short* __restrict__ wt1, const float* __restrict__ b1,
    const unsigned short* __restrict__ wt2, const float* __restrict__ b2,
    const unsigned short* __restrict__ ht, const float* __restrict__ hbp,
    float* __restrict__ outp)
{
    __shared__ float lds[4][16 * LSTRIDE];
    const int lane = threadIdx.x & 63;
    const int c = lane & 15, q = lane >> 4;
    float* L = lds[threadIdx.x >> 6];

    const int gwave  = (blockIdx.x * blockDim.x + threadIdx.x) >> 6;
    const int nwaves = (gridDim.x * blockDim.x) >> 6;

    bf16x8 a1[4][2], a2[4][2], a3[2][2];
#pragma unroll
    for (int mt = 0; mt < 4; ++mt)
#pragma unroll
        for (int ks = 0; ks < 2; ++ks) {
            a1[mt][ks] = __builtin_bit_cast(bf16x8,
                *(const ushort8*)(wt1 + (mt * 16 + c) * 64 + ks * 32 + q * 8));
            a2[mt][ks] = __builtin_bit_cast(bf16x8,
                *(const ushort8*)(wt2 + (mt * 16 + c) * 64 + ks * 32 + q * 8));
        }
#pragma unroll
    for (int mt = 0; mt < 2; ++mt)
#pragma unroll
        for (int ks = 0; ks < 2; ++ks)
            a3[mt][ks] = __builtin_bit_cast(bf16x8,
                *(const ushort8*)(ht + (mt * 16 + c) * 64 + ks * 32 + q * 8));
    f32x4 b1v[4], b2v[4], hbv[2];
#pragma unroll
    for (int mt = 0; mt < 4; ++mt) {
        b1v[mt] = *(const f32x4*)(b1 + mt * 16 + q * 4);
        b2v[mt] = *(const f32x4*)(b2 + mt * 16 + q * 4);
    }
#pragma unroll
    for (int mt = 0; mt < 2; ++mt)
        hbv[mt] = *(const f32x4*)(hbp + mt * 16 + q * 4);

    const int ntiles = N_NODES / 16;
    for (int tile = gwave; tile < ntiles; tile += nwaves) {
        const int n0 = tile * 16;
        const unsigned short* xr = xbf + (size_t)(n0 + c) * 64;
        const float* ar = agg + (size_t)(n0 + c) * 64;

        bf16x8 hb[2];
#pragma unroll
        for (int ks = 0; ks < 2; ++ks) {
            const int o = ks * 32 + q * 8;
            const int b0 = o >> 2, b1i = b0 + 1;
            const int pb0 = (b0 & 3) * 16 + (b0 >> 2) * 4;
            const int pb1 = (b1i & 3) * 16 + (b1i >> 2) * 4;
            const u16x4 xa4 = *(const u16x4*)(xr + pb0);
            const u16x4 xb4 = *(const u16x4*)(xr + pb1);
            const f32x4 aa = *(const f32x4*)(ar + pb0);
            const f32x4 ab = *(const f32x4*)(ar + pb1);
            ushort8 u;
#pragma unroll
            for (int i = 0; i < 4; ++i) {
                u[i]     = f2bf(bf2f(xa4[i]) + aa[i]);
                u[4 + i] = f2bf(bf2f(xb4[i]) + ab[i]);
            }
            hb[ks] = __builtin_bit_cast(bf16x8, u);
        }

        f32x4 acc[4];
#pragma unroll
        for (int mt = 0; mt < 4; ++mt) {
            acc[mt] = __builtin_amdgcn_mfma_f32_16x16x32_bf16(
                a1[mt][0], hb[0], (f32x4){0.f, 0.f, 0.f, 0.f}, 0, 0, 0);
            acc[mt] = __builtin_amdgcn_mfma_f32_16x16x32_bf16(
                a1[mt][1], hb[1], acc[mt], 0, 0, 0);
        }

#pragma unroll
        for (int mt = 0; mt < 4; ++mt) {
            f32x4 t;
#pragma unroll
            for (int r = 0; r < 4; ++r) t[r] = fmaxf(acc[mt][r] + b1v[mt][r], 0.f);
            *(f32x4*)(L + c * LSTRIDE + mt * 16 + q * 4) = t;
        }
        asm volatile("s_waitcnt lgkmcnt(0)" ::: "memory");

        bf16x8 tb[2];
#pragma unroll
        for (int ks = 0; ks < 2; ++ks) {
            const f32x4 lo = *(const f32x4*)(L + c * LSTRIDE + ks * 32 + q * 8);
            const f32x4 hi = *(const f32x4*)(L + c * LSTRIDE + ks * 32 + q * 8 + 4);
            ushort8 u;
            u[0] = f2bf(lo[0]); u[1] = f2bf(lo[1]); u[2] = f2bf(lo[2]); u[3] = f2bf(lo[3]);
            u[4] = f2bf(hi[0]); u[5] = f2bf(hi[1]); u[6] = f2bf(hi[2]); u[7] = f2bf(hi[3]);
            tb[ks] = __builtin_bit_cast(bf16x8, u);
        }
        asm volatile("s_waitcnt lgkmcnt(0)" ::: "memory");

#pragma unroll
        for (int mt = 0; mt < 4; ++mt) {
            acc[mt] = __builtin_amdgcn_mfma_f32_16x16x32_bf16(
                a2[mt][0], tb[0], (f32x4){0.f, 0.f, 0.f, 0.f}, 0, 0, 0);
            acc[mt] = __builtin_amdgcn_mfma_f32_16x16x32_bf16(
                a2[mt][1], tb[1], acc[mt], 0, 0, 0);
        }

#pragma unroll
        for (int mt = 0; mt < 4; ++mt) {
            f32x4 t;
#pragma unroll
            for (int r = 0; r < 4; ++r) t[r] = fmaxf(acc[mt][r] + b2v[mt][r], 0.f);
            *(f32x4*)(L + c * LSTRIDE + mt * 16 + q * 4) = t;
        }
        asm volatile("s_waitcnt lgkmcnt(0)" ::: "memory");

        bf16x8 ub[2];
#pragma unroll
        for (int ks = 0; ks < 2; ++ks) {
            const f32x4 lo = *(const f32x4*)(L + c * LSTRIDE + ks * 32 + q * 8);
            const f32x4 hi = *(const f32x4*)(L + c * LSTRIDE + ks * 32 + q * 8 + 4);
            ushort8 u;
            u[0] = f2bf(lo[0]); u[1] = f2bf(lo[1]); u[2] = f2bf(lo[2]); u[3] = f2bf(lo[3]);
            u[4] = f2bf(hi[0]); u[5] = f2bf(hi[1]); u[6] = f2bf(hi[2]); u[7] = f2bf(hi[3]);
            ub[ks] = __builtin_bit_cast(bf16x8, u);
        }
        asm volatile("s_waitcnt lgkmcnt(0)" ::: "memory");

        f32x4 acc3[2];
#pragma unroll
        for (int mt = 0; mt < 2; ++mt) {
            acc3[mt] = __builtin_amdgcn_mfma_f32_16x16x32_bf16(
                a3[mt][0], ub[0], (f32x4){0.f, 0.f, 0.f, 0.f}, 0, 0, 0);
            acc3[mt] = __builtin_amdgcn_mfma_f32_16x16x32_bf16(
                a3[mt][1], ub[1], acc3[mt], 0, 0, 0);
        }

        float* outr = outp + (size_t)(n0 + c) * 32;
#pragma unroll
        for (int mt = 0; mt < 2; ++mt) {
            f32x4 u;
#pragma unroll
            for (int r = 0; r < 4; ++r) u[r] = acc3[mt][r] + hbv[mt][r];
            *(f32x4*)(outr + mt * 16 + q * 4) = u;
        }
    }
}

extern "C" void kernel_launch(void* const* d_in, const int* in_sizes, int n_in,
                              void* d_out, int out_size, void* d_ws, size_t ws_size,
                              hipStream_t stream) {
    const float* x     = (const float*)d_in[0];
    const float* ea    = (const float*)d_in[1];
    const int*   ei    = (const int*)  d_in[2];
    const float* c1lw  = (const float*)d_in[3];
    const float* c1lb  = (const float*)d_in[4];
    const float* c1w1  = (const float*)d_in[5];
    const float* c1b1  = (const float*)d_in[6];
    const float* c1w2  = (const float*)d_in[7];
    const float* c1b2  = (const float*)d_in[8];
    const float* c2lw  = (const float*)d_in[9];
    const float* c2lb  = (const float*)d_in[10];
    const float* c2w1  = (const float*)d_in[11];
    const float* c2b1  = (const float*)d_in[12];
    const float* c2w2  = (const float*)d_in[13];
    const float* c2b2  = (const float*)d_in[14];
    const float* hw    = (const float*)d_in[15];
    const float* hb    = (const float*)d_in[16];

    const int* srcp = ei;
    const int* dstp = ei + N_EDGES;

    float*          agg = (float*)d_ws;                                  // [N,64] f32 (fallback)
    unsigned short* xbf = (unsigned short*)(agg + (size_t)N_NODES * 64); // [N,64] bf16
    unsigned short* hbf = xbf + (size_t)N_NODES * 64;                    // [N,64] bf16
    int*   cnt       = (int*)(hbf + (size_t)N_NODES * 64);               // [N]
    int*   offs      = cnt + N_NODES;                                    // [N+1]
    int*   offs_work = offs + (N_NODES + 1);                             // [N+1]
    int*   bsum      = offs_work + (N_NODES + 1);                        // [256]
    int*   bpre      = bsum + 256;                                       // [256]
    size_t wtb_off = ((size_t)((char*)(bpre + 256) - (char*)d_ws) + 63) & ~(size_t)63;
    unsigned short* wtb = (unsigned short*)((char*)d_ws + wtb_off);      // [22528]
    unsigned short* lt1  = wtb;
    unsigned short* wt1a = wtb + 2048;
    unsigned short* wt1b = wtb + 6144;
    unsigned short* lt2  = wtb + 10240;
    unsigned short* wt2a = wtb + 12288;
    unsigned short* wt2b = wtb + 16384;
    unsigned short* ht   = wtb + 20480;
    int*   ssrc = (int*)(wtb + WTB_ELEMS);                               // [E]
    size_t tail_off = ((size_t)((char*)(ssrc + N_EDGES) - (char*)d_ws) + 63) & ~(size_t)63;
    unsigned short* ea_s = (unsigned short*)((char*)d_ws + tail_off);    // [E,32] bf16
    int*            perm_tail = (int*)((char*)d_ws + tail_off);          // fallback [E]
    const bool primary = ws_size >= tail_off + (size_t)N_EDGES * 32 * sizeof(unsigned short) + 64;

    float* outp = (float*)d_out;
    const int SCAN_G = (N_NODES + 255) / 256;

    // CSR build + weight prep (shared by both paths)
    hipMemsetAsync(cnt, 0, N_NODES * sizeof(int), stream);
    hipLaunchKernelGGL(hist_xbf, dim3(2048), dim3(256), 0, stream, dstp, cnt, x, xbf);
    hipLaunchKernelGGL(scan_p1, dim3(256),    dim3(256), 0, stream, cnt, bsum);
    hipLaunchKernelGGL(scan_p2, dim3(1),      dim3(256), 0, stream, bsum, bpre, offs);
    hipLaunchKernelGGL(scan_p3, dim3(SCAN_G), dim3(256), 0, stream, cnt, bpre, offs, offs_work);
    hipLaunchKernelGGL(w_prep, dim3((WTB_ELEMS + 255) / 256), dim3(256), 0, stream,
                       c1lw, c1w1, c1w2, c2lw, c2w1, c2w2, hw, wtb);

    if (primary) {
        hipLaunchKernelGGL(csr_scatter_ea, dim3((N_EDGES + 255) / 256), dim3(256),
                           0, stream, ea, srcp, dstp, offs_work, ssrc, ea_s);
        hipLaunchKernelGGL(gine_conv1, dim3(800), dim3(256), 0, stream,
                           xbf, x, ea_s, ssrc, offs, lt1, c1lb,
                           wt1a, c1b1, wt1b, c1b2, hbf);
        hipLaunchKernelGGL(gine_conv2_head, dim3(800), dim3(256), 0, stream,
                           hbf, ea_s, ssrc, offs, lt2, c2lb,
                           wt2a, c2b1, wt2b, c2b2, ht, hb, outp);
    } else {
        // small-ws fallback: perm in tail, per-node gathers read ea randomly
        int* perm = perm_tail;
        hipLaunchKernelGGL(csr_scatter_perm_srcs, dim3(2048), dim3(256), 0, stream,
                           dstp, offs_work, srcp, perm, ssrc);
        hipLaunchKernelGGL(gine_gather_fb, dim3(4096), dim3(256), 0, stream,
                           xbf, ea, perm, ssrc, offs, lt1, c1lb, agg);
        hipLaunchKernelGGL(gine_node_mfma, dim3(800), dim3(256), 0, stream,
                           x, agg, wt1a, c1b1, wt1b, c1b2, hbf);
        hipLaunchKernelGGL(gine_gather_fb, dim3(4096), dim3(256), 0, stream,
                           hbf, ea, perm, ssrc, offs, lt2, c2lb, agg);
        hipLaunchKernelGGL(gine_node_head_mfma, dim3(800), dim3(256), 0, stream,
                           hbf, agg, wt2a, c2b1, wt2b, c2b2, ht, hb, outp);
    }
}

// Round 8
// 368.590 us; speedup vs baseline: 1.1075x; 1.1075x over previous
//
#include <hip/hip_runtime.h>

#define N_NODES 50000
#define N_EDGES 800000
#define LSTRIDE 68

typedef __bf16 bf16x8 __attribute__((ext_vector_type(8)));
typedef unsigned short ushort8 __attribute__((ext_vector_type(8)));
typedef unsigned short u16x4 __attribute__((ext_vector_type(4)));
typedef float f32x4 __attribute__((ext_vector_type(4)));

__device__ __forceinline__ unsigned short f2bf(float f) {
    unsigned u = __builtin_bit_cast(unsigned, f);
    u += 0x7fffu + ((u >> 16) & 1u);
    return (unsigned short)(u >> 16);
}
__device__ __forceinline__ float bf2f(unsigned short u) {
    return __builtin_bit_cast(float, (unsigned)u << 16);
}

__device__ __forceinline__ f32x4 shfl_xor4(f32x4 v, int m) {
    f32x4 r;
    r[0] = __shfl_xor(v[0], m); r[1] = __shfl_xor(v[1], m);
    r[2] = __shfl_xor(v[2], m); r[3] = __shfl_xor(v[3], m);
    return r;
}
__device__ __forceinline__ f32x4 sel4(bool p, f32x4 a, f32x4 b) {
    f32x4 r;
    r[0] = p ? a[0] : b[0]; r[1] = p ? a[1] : b[1];
    r[2] = p ? a[2] : b[2]; r[3] = p ? a[3] : b[3];
    return r;
}

// Permuted channel order (agg rows, x_bf, h1_bf):
//   pos(ch) = ch[3:2]<<4 | ch[5:4]<<2 | ch[1:0]
//
// [R1] scattered 64B data writes amplify L2 RMW (WRITE 53->78MB); tolerable.
// [R2] random reads inside per-node gather loops are latency-bound.
// [R3] nt-stores on scattered rows bypass L2 write-combine (77->177MB). Never.
// [R4] grid.sync() ~140us each — cooperative multi-phase is dead.
// [R5] scattered global fp32 atomics: ~64B DRAM txn each. Dead.
// [R6] weight pretranspose + hist-fused x2bf: tie (375.98) — keep (no cost).
// [R7a] atomic-pos scatter: WORSE (70->76us, WRITE 77.6->102MB) — keep
//       hist-assigned rank (pure-load address path in the scatter).
// [R7b] gather+MLP fusion: WORSE (14.5% occupancy, serialized per-node
//       chains). Keep the split gather (one node per wave in flight).
// This round: R6 exactly + 4-lanes-per-edge scatter (one wave store
// instruction = 16 complete 64B rows; 4x TLP on the addr chain).

// Transposed bf16 weight blob layout (offsets in u16 elements):
//   lt1  [64 out][32 k]  @ 0       (c1 lin)
//   wt1a [64][64]        @ 2048    (c1 w1)
//   wt1b [64][64]        @ 6144    (c1 w2)
//   lt2  [64][32]        @ 10240   (c2 lin)
//   wt2a [64][64]        @ 12288   (c2 w1)
//   wt2b [64][64]        @ 16384   (c2 w2)
//   ht   [32 out][64 k]  @ 20480   (head)
#define WTB_ELEMS 22528

__global__ __launch_bounds__(256) void w_prep(
    const float* __restrict__ c1lw, const float* __restrict__ c1w1,
    const float* __restrict__ c1w2, const float* __restrict__ c2lw,
    const float* __restrict__ c2w1, const float* __restrict__ c2w2,
    const float* __restrict__ hw, unsigned short* __restrict__ wtb) {
    const int i = blockIdx.x * 256 + threadIdx.x;
    if (i >= WTB_ELEMS) return;
    float v;
    if (i < 2048)        { const int j = i;          v = c1lw[(j & 31) * 64 + (j >> 5)]; }
    else if (i < 6144)   { const int j = i - 2048;   v = c1w1[(j & 63) * 64 + (j >> 6)]; }
    else if (i < 10240)  { const int j = i - 6144;   v = c1w2[(j & 63) * 64 + (j >> 6)]; }
    else if (i < 12288)  { const int j = i - 10240;  v = c2lw[(j & 31) * 64 + (j >> 5)]; }
    else if (i < 16384)  { const int j = i - 12288;  v = c2w1[(j & 63) * 64 + (j >> 6)]; }
    else if (i < 20480)  { const int j = i - 16384;  v = c2w2[(j & 63) * 64 + (j >> 6)]; }
    else                 { const int j = i - 20480;  v = hw[(j & 63) * 32 + (j >> 6)]; }
    wtb[i] = f2bf(v);
}

// ======================= CSR build =======================
// histogram + rank, with x->bf16 (permuted) fused in (independent streaming
// work overlaps the returning-atomic latency). [R6 proven]
__global__ __launch_bounds__(256) void hist_rank_xbf(
    const int* __restrict__ dstp, int* __restrict__ cnt, int* __restrict__ rank,
    const float* __restrict__ x, unsigned short* __restrict__ xbf) {
    const int tid = blockIdx.x * blockDim.x + threadIdx.x;
    const int nthr = gridDim.x * blockDim.x;
    for (int e = tid; e < N_EDGES; e += nthr)
        rank[e] = atomicAdd(&cnt[dstp[e]], 1);
    for (int i = tid; i < N_NODES * 16; i += nthr) {
        const int n = i >> 4, b = i & 15;
        const float4 v = *(const float4*)(x + (size_t)n * 64 + b * 4);
        u16x4 o;
        o[0] = f2bf(v.x); o[1] = f2bf(v.y); o[2] = f2bf(v.z); o[3] = f2bf(v.w);
        *(u16x4*)(xbf + (size_t)n * 64 + (b & 3) * 16 + (b >> 2) * 4) = o;
    }
}

__global__ __launch_bounds__(256) void scan_p1(const int* __restrict__ cnt,
                                               int* __restrict__ bsum) {
    __shared__ int sm[256];
    const int t = threadIdx.x;
    const int idx = blockIdx.x * 256 + t;
    sm[t] = (idx < N_NODES) ? cnt[idx] : 0;
    __syncthreads();
    for (int off = 128; off > 0; off >>= 1) {
        if (t < off) sm[t] += sm[t + off];
        __syncthreads();
    }
    if (t == 0) bsum[blockIdx.x] = sm[0];
}

__global__ __launch_bounds__(256) void scan_p2(const int* __restrict__ bsum,
                                               int* __restrict__ bpre,
                                               int* __restrict__ offs) {
    __shared__ int sm[256];
    const int t = threadIdx.x;
    int v = bsum[t];
    sm[t] = v;
    __syncthreads();
    for (int off = 1; off < 256; off <<= 1) {
        int u = (t >= off) ? sm[t - off] : 0;
        __syncthreads();
        sm[t] += u;
        __syncthreads();
    }
    bpre[t] = sm[t] - v;
    if (t == 255) offs[N_NODES] = sm[255];
}

__global__ __launch_bounds__(256) void scan_p3(const int* __restrict__ cnt,
                                               const int* __restrict__ bpre,
                                               int* __restrict__ offs) {
    __shared__ int sm[256];
    const int t = threadIdx.x;
    const int idx = blockIdx.x * 256 + t;
    const int v = (idx < N_NODES) ? cnt[idx] : 0;
    sm[t] = v;
    __syncthreads();
    for (int off = 1; off < 256; off <<= 1) {
        int u = (t >= off) ? sm[t - off] : 0;
        __syncthreads();
        sm[t] += u;
        __syncthreads();
    }
    if (idx < N_NODES) offs[idx] = bpre[blockIdx.x] + sm[t] - v;
}

// fallback-only index scatter (perm + ssrc)
__global__ __launch_bounds__(256) void csr_scatter_perm_srcs(
    const int* __restrict__ dstp, const int* __restrict__ rank,
    const int* __restrict__ offs, const int* __restrict__ srcp,
    int* __restrict__ perm, int* __restrict__ ssrc) {
    for (int e = blockIdx.x * blockDim.x + threadIdx.x; e < N_EDGES;
         e += gridDim.x * blockDim.x) {
        const int pos = offs[dstp[e]] + rank[e];
        perm[pos] = e;
        ssrc[pos] = srcp[e];
    }
}

// primary fused data scatter, 4 LANES PER EDGE: groups of 4 consecutive
// lanes handle one edge; each lane reads 32B contiguous (group = full 128B
// line) and stores 16B so the group writes one COMPLETE 64B row in a single
// wave store instruction (16 whole rows/instruction vs 64 partial). Address
// path is pure loads (rank precomputed — R7a). Regular stores (R3).
__global__ __launch_bounds__(256) void csr_scatter_ea4(
    const float* __restrict__ ea, const int* __restrict__ srcp,
    const int* __restrict__ dstp, const int* __restrict__ rank,
    const int* __restrict__ offs, int* __restrict__ ssrc,
    unsigned short* __restrict__ ea_s) {
    const int t4 = blockIdx.x * 256 + threadIdx.x;
    const int e = t4 >> 2;
    const int sub = t4 & 3;
    if (e >= N_EDGES) return;
    const int pos = offs[dstp[e]] + rank[e];   // same line across the 4 lanes
    if (sub == 0) ssrc[pos] = srcp[e];
    const float* er = ea + (size_t)e * 32 + sub * 8;
    const float4 v0 = *(const float4*)er;
    const float4 v1 = *(const float4*)(er + 4);
    ushort8 u;
    u[0] = f2bf(v0.x); u[1] = f2bf(v0.y); u[2] = f2bf(v0.z); u[3] = f2bf(v0.w);
    u[4] = f2bf(v1.x); u[5] = f2bf(v1.y); u[6] = f2bf(v1.z); u[7] = f2bf(v1.w);
    *(ushort8*)(ea_s + (size_t)pos * 32 + sub * 8) = u;
}

// ---------------------------------------------------------------------------
// Per-node gather (R1/R6 structure, proven): one wave per node; bf16 ea_s
// coalesced; weights from transposed bf16 blob (1 vector load per fragment).
// ---------------------------------------------------------------------------
__global__ __launch_bounds__(256) void gine_gather_bf(
    const unsigned short* __restrict__ xbf,   // [N,64] bf16 permuted
    const unsigned short* __restrict__ eas,   // [E,32] bf16 dst-sorted
    const int*   __restrict__ ssrc,
    const int*   __restrict__ offs,
    const unsigned short* __restrict__ lt,    // [64 out][32 k] bf16
    const float* __restrict__ linB,
    float*       __restrict__ agg)            // [N,64] fp32 permuted
{
    const int lane = threadIdx.x & 63;
    const int gwave  = (blockIdx.x * blockDim.x + threadIdx.x) >> 6;
    const int nwaves = (gridDim.x * blockDim.x) >> 6;
    const int c = lane & 15;
    const int q = lane >> 4;

    bf16x8 wf[4];
#pragma unroll
    for (int mt = 0; mt < 4; ++mt)
        wf[mt] = __builtin_bit_cast(bf16x8,
            *(const ushort8*)(lt + (mt * 16 + c) * 32 + q * 8));
    f32x4 biasv[4];
#pragma unroll
    for (int mt = 0; mt < 4; ++mt)
        biasv[mt] = *(const f32x4*)(linB + mt * 16 + q * 4);

    for (int n = gwave; n < N_NODES; n += nwaves) {
        const int start = offs[n];
        const int end   = offs[n + 1];

        const int pidx = (start + lane < end) ? (start + lane)
                                              : ((end > start) ? end - 1 : 0);
        const int sl = ssrc[pidx];

        f32x4 s0 = {0.f,0.f,0.f,0.f}, s1 = {0.f,0.f,0.f,0.f};
        f32x4 s2 = {0.f,0.f,0.f,0.f}, s3 = {0.f,0.f,0.f,0.f};

        int t = 0;
        for (int base = start; base < end; base += 16, ++t) {
            const int eidx = base + c;
            const bool valid = eidx < end;
            const int ecl = valid ? eidx : end - 1;

            const bf16x8 bf = __builtin_bit_cast(bf16x8,
                *(const ushort8*)(eas + (size_t)ecl * 32 + q * 8));

            int s;
            if (t < 4) s = __shfl(sl, (t << 4) + c);
            else       s = ssrc[ecl];

            f32x4 acc[4];
            acc[0] = __builtin_amdgcn_mfma_f32_16x16x32_bf16(wf[0], bf, biasv[0], 0, 0, 0);
            acc[1] = __builtin_amdgcn_mfma_f32_16x16x32_bf16(wf[1], bf, biasv[1], 0, 0, 0);
            acc[2] = __builtin_amdgcn_mfma_f32_16x16x32_bf16(wf[2], bf, biasv[2], 0, 0, 0);
            acc[3] = __builtin_amdgcn_mfma_f32_16x16x32_bf16(wf[3], bf, biasv[3], 0, 0, 0);

            const unsigned short* xr = xbf + (size_t)s * 64 + q * 16;
            const ushort8 xa = *(const ushort8*)xr;
            const ushort8 xb = *(const ushort8*)(xr + 8);

            const float NEG = -3.0e38f;
#pragma unroll
            for (int r = 0; r < 4; ++r) {
                s0[r] += fmaxf((valid ? bf2f(xa[r])     : NEG) + acc[0][r], 0.f);
                s1[r] += fmaxf((valid ? bf2f(xa[4 + r]) : NEG) + acc[1][r], 0.f);
                s2[r] += fmaxf((valid ? bf2f(xb[r])     : NEG) + acc[2][r], 0.f);
                s3[r] += fmaxf((valid ? bf2f(xb[4 + r]) : NEG) + acc[3][r], 0.f);
            }
        }

        f32x4 t0 = sel4((c & 8) != 0, s2, s0) + shfl_xor4(sel4((c & 8) != 0, s0, s2), 8);
        f32x4 t1 = sel4((c & 8) != 0, s3, s1) + shfl_xor4(sel4((c & 8) != 0, s1, s3), 8);
        f32x4 u = sel4((c & 4) != 0, t1, t0) + shfl_xor4(sel4((c & 4) != 0, t0, t1), 4);
        float v0 = ((c & 2) ? u[2] : u[0]) + __shfl_xor((c & 2) ? u[0] : u[2], 2);
        float v1 = ((c & 2) ? u[3] : u[1]) + __shfl_xor((c & 2) ? u[1] : u[3], 2);
        float w = ((c & 1) ? v1 : v0) + __shfl_xor((c & 1) ? v0 : v1, 1);

        agg[(size_t)n * 64 + lane] = w;
    }
}

// fallback per-node gather: ea fp32 via perm (random reads)
__global__ __launch_bounds__(256) void gine_gather_fb(
    const unsigned short* __restrict__ xbf, const float* __restrict__ ea,
    const int* __restrict__ perm, const int* __restrict__ ssrc,
    const int* __restrict__ offs, const unsigned short* __restrict__ lt,
    const float* __restrict__ linB, float* __restrict__ agg)
{
    const int lane = threadIdx.x & 63;
    const int gwave  = (blockIdx.x * blockDim.x + threadIdx.x) >> 6;
    const int nwaves = (gridDim.x * blockDim.x) >> 6;
    const int c = lane & 15;
    const int q = lane >> 4;

    bf16x8 wf[4];
#pragma unroll
    for (int mt = 0; mt < 4; ++mt)
        wf[mt] = __builtin_bit_cast(bf16x8,
            *(const ushort8*)(lt + (mt * 16 + c) * 32 + q * 8));
    f32x4 biasv[4];
#pragma unroll
    for (int mt = 0; mt < 4; ++mt)
        biasv[mt] = *(const f32x4*)(linB + mt * 16 + q * 4);

    for (int n = gwave; n < N_NODES; n += nwaves) {
        const int start = offs[n];
        const int end   = offs[n + 1];
        const int pidx = (start + lane < end) ? (start + lane)
                                              : ((end > start) ? end - 1 : 0);
        const int sl = ssrc[pidx];

        f32x4 s0 = {0.f,0.f,0.f,0.f}, s1 = {0.f,0.f,0.f,0.f};
        f32x4 s2 = {0.f,0.f,0.f,0.f}, s3 = {0.f,0.f,0.f,0.f};

        int t = 0;
        for (int base = start; base < end; base += 16, ++t) {
            const int eidx = base + c;
            const bool valid = eidx < end;
            const int ecl = valid ? eidx : end - 1;

            const int e = perm[ecl];
            const float* ap = ea + (size_t)e * 32 + q * 8;
            const float4 a0 = *(const float4*)ap;
            const float4 a1 = *(const float4*)(ap + 4);
            ushort8 ub;
            ub[0] = f2bf(a0.x); ub[1] = f2bf(a0.y); ub[2] = f2bf(a0.z); ub[3] = f2bf(a0.w);
            ub[4] = f2bf(a1.x); ub[5] = f2bf(a1.y); ub[6] = f2bf(a1.z); ub[7] = f2bf(a1.w);
            const bf16x8 bf = __builtin_bit_cast(bf16x8, ub);

            int s;
            if (t < 4) s = __shfl(sl, (t << 4) + c);
            else       s = ssrc[ecl];

            f32x4 acc[4];
            acc[0] = __builtin_amdgcn_mfma_f32_16x16x32_bf16(wf[0], bf, biasv[0], 0, 0, 0);
            acc[1] = __builtin_amdgcn_mfma_f32_16x16x32_bf16(wf[1], bf, biasv[1], 0, 0, 0);
            acc[2] = __builtin_amdgcn_mfma_f32_16x16x32_bf16(wf[2], bf, biasv[2], 0, 0, 0);
            acc[3] = __builtin_amdgcn_mfma_f32_16x16x32_bf16(wf[3], bf, biasv[3], 0, 0, 0);

            const unsigned short* xr = xbf + (size_t)s * 64 + q * 16;
            const ushort8 xa = *(const ushort8*)xr;
            const ushort8 xb = *(const ushort8*)(xr + 8);

            const float NEG = -3.0e38f;
#pragma unroll
            for (int r = 0; r < 4; ++r) {
                s0[r] += fmaxf((valid ? bf2f(xa[r])     : NEG) + acc[0][r], 0.f);
                s1[r] += fmaxf((valid ? bf2f(xa[4 + r]) : NEG) + acc[1][r], 0.f);
                s2[r] += fmaxf((valid ? bf2f(xb[r])     : NEG) + acc[2][r], 0.f);
                s3[r] += fmaxf((valid ? bf2f(xb[4 + r]) : NEG) + acc[3][r], 0.f);
            }
        }

        f32x4 t0 = sel4((c & 8) != 0, s2, s0) + shfl_xor4(sel4((c & 8) != 0, s0, s2), 8);
        f32x4 t1 = sel4((c & 8) != 0, s3, s1) + shfl_xor4(sel4((c & 8) != 0, s1, s3), 8);
        f32x4 u = sel4((c & 4) != 0, t1, t0) + shfl_xor4(sel4((c & 4) != 0, t0, t1), 4);
        float v0 = ((c & 2) ? u[2] : u[0]) + __shfl_xor((c & 2) ? u[0] : u[2], 2);
        float v1 = ((c & 2) ? u[3] : u[1]) + __shfl_xor((c & 2) ? u[1] : u[3], 2);
        float w = ((c & 1) ? v1 : v0) + __shfl_xor((c & 1) ? v0 : v1, 1);

        agg[(size_t)n * 64 + lane] = w;
    }
}

// ---------------------------------------------------------------------------
// Node MLP via MFMA (one wave = 16 nodes), per-wave LDS transpose.
// Weights from transposed bf16 blob: 1 vector load per fragment.
// ---------------------------------------------------------------------------
__global__ __launch_bounds__(256) void gine_node_mfma(
    const float* __restrict__ xin, const float* __restrict__ agg,
    const unsigned short* __restrict__ wt1,   // [64][64] bf16 (w1^T)
    const float* __restrict__ b1,
    const unsigned short* __restrict__ wt2,   // [64][64] bf16 (w2^T)
    const float* __restrict__ b2,
    unsigned short* __restrict__ hbf)          // [N,64] bf16 permuted
{
    __shared__ float lds[4][16 * LSTRIDE];
    const int lane = threadIdx.x & 63;
    const int c = lane & 15, q = lane >> 4;
    float* L = lds[threadIdx.x >> 6];

    const int gwave  = (blockIdx.x * blockDim.x + threadIdx.x) >> 6;
    const int nwaves = (gridDim.x * blockDim.x) >> 6;

    bf16x8 a1[4][2], a2[4][2];
#pragma unroll
    for (int mt = 0; mt < 4; ++mt)
#pragma unroll
        for (int ks = 0; ks < 2; ++ks) {
            a1[mt][ks] = __builtin_bit_cast(bf16x8,
                *(const ushort8*)(wt1 + (mt * 16 + c) * 64 + ks * 32 + q * 8));
            a2[mt][ks] = __builtin_bit_cast(bf16x8,
                *(const ushort8*)(wt2 + (mt * 16 + c) * 64 + ks * 32 + q * 8));
        }
    f32x4 b1v[4], b2v[4];
#pragma unroll
    for (int mt = 0; mt < 4; ++mt) {
        b1v[mt] = *(const f32x4*)(b1 + mt * 16 + q * 4);
        b2v[mt] = *(const f32x4*)(b2 + mt * 16 + q * 4);
    }

    const int ntiles = N_NODES / 16;
    for (int tile = gwave; tile < ntiles; tile += nwaves) {
        const int n0 = tile * 16;
        const float* xr = xin + (size_t)(n0 + c) * 64;
        const float* ar = agg + (size_t)(n0 + c) * 64;

        bf16x8 hb[2];
#pragma unroll
        for (int ks = 0; ks < 2; ++ks) {
            const int o = ks * 32 + q * 8;
            const int b0 = o >> 2, b1i = b0 + 1;
            const float4 xa = *(const float4*)(xr + o);
            const float4 xb = *(const float4*)(xr + o + 4);
            const float4 aa = *(const float4*)(ar + ((b0 & 3) * 16 + (b0 >> 2) * 4));
            const float4 ab = *(const float4*)(ar + ((b1i & 3) * 16 + (b1i >> 2) * 4));
            ushort8 u;
            u[0] = f2bf(xa.x + aa.x); u[1] = f2bf(xa.y + aa.y);
            u[2] = f2bf(xa.z + aa.z); u[3] = f2bf(xa.w + aa.w);
            u[4] = f2bf(xb.x + ab.x); u[5] = f2bf(xb.y + ab.y);
            u[6] = f2bf(xb.z + ab.z); u[7] = f2bf(xb.w + ab.w);
            hb[ks] = __builtin_bit_cast(bf16x8, u);
        }

        f32x4 acc[4];
#pragma unroll
        for (int mt = 0; mt < 4; ++mt) {
            acc[mt] = __builtin_amdgcn_mfma_f32_16x16x32_bf16(
                a1[mt][0], hb[0], (f32x4){0.f, 0.f, 0.f, 0.f}, 0, 0, 0);
            acc[mt] = __builtin_amdgcn_mfma_f32_16x16x32_bf16(
                a1[mt][1], hb[1], acc[mt], 0, 0, 0);
        }

#pragma unroll
        for (int mt = 0; mt < 4; ++mt) {
            f32x4 t;
#pragma unroll
            for (int r = 0; r < 4; ++r) t[r] = fmaxf(acc[mt][r] + b1v[mt][r], 0.f);
            *(f32x4*)(L + c * LSTRIDE + mt * 16 + q * 4) = t;
        }
        asm volatile("s_waitcnt lgkmcnt(0)" ::: "memory");

        bf16x8 tb[2];
#pragma unroll
        for (int ks = 0; ks < 2; ++ks) {
            const f32x4 lo = *(const f32x4*)(L + c * LSTRIDE + ks * 32 + q * 8);
            const f32x4 hi = *(const f32x4*)(L + c * LSTRIDE + ks * 32 + q * 8 + 4);
            ushort8 u;
            u[0] = f2bf(lo[0]); u[1] = f2bf(lo[1]); u[2] = f2bf(lo[2]); u[3] = f2bf(lo[3]);
            u[4] = f2bf(hi[0]); u[5] = f2bf(hi[1]); u[6] = f2bf(hi[2]); u[7] = f2bf(hi[3]);
            tb[ks] = __builtin_bit_cast(bf16x8, u);
        }
        asm volatile("s_waitcnt lgkmcnt(0)" ::: "memory");

#pragma unroll
        for (int mt = 0; mt < 4; ++mt) {
            acc[mt] = __builtin_amdgcn_mfma_f32_16x16x32_bf16(
                a2[mt][0], tb[0], (f32x4){0.f, 0.f, 0.f, 0.f}, 0, 0, 0);
            acc[mt] = __builtin_amdgcn_mfma_f32_16x16x32_bf16(
                a2[mt][1], tb[1], acc[mt], 0, 0, 0);
        }

        unsigned short* hr = hbf + (size_t)(n0 + c) * 64 + q * 16;
        ushort8 lo8, hi8;
#pragma unroll
        for (int r = 0; r < 4; ++r) {
            lo8[r]     = f2bf(fmaxf(acc[0][r] + b2v[0][r], 0.f));
            lo8[4 + r] = f2bf(fmaxf(acc[1][r] + b2v[1][r], 0.f));
            hi8[r]     = f2bf(fmaxf(acc[2][r] + b2v[2][r], 0.f));
            hi8[4 + r] = f2bf(fmaxf(acc[3][r] + b2v[3][r], 0.f));
        }
        *(ushort8*)hr = lo8;
        *(ushort8*)(hr + 8) = hi8;
    }
}

// conv2 + head: xin is permuted bf16 h1
__global__ __launch_bounds__(256) void gine_node_head_mfma(
    const unsigned short* __restrict__ xbf, const float* __restrict__ agg,
    const unsigned short* __restrict__ wt1, const float* __restrict__ b1,
    const unsigned short* __restrict__ wt2, const float* __restrict__ b2,
    const unsigned short* __restrict__ ht,   // [32 out][64 k] bf16 (head^T)
    const float* __restrict__ hbp,
    float* __restrict__ outp)
{
    __shared__ float lds[4][16 * LSTRIDE];
    const int lane = threadIdx.x & 63;
    const int c = lane & 15, q = lane >> 4;
    float* L = lds[threadIdx.x >> 6];

    const int gwave  = (blockIdx.x * blockDim.x + threadIdx.x) >> 6;
    const int nwaves = (gridDim.x * blockDim.x) >> 6;

    bf16x8 a1[4][2], a2[4][2], a3[2][2];
#pragma unroll
    for (int mt = 0; mt < 4; ++mt)
#pragma unroll
        for (int ks = 0; ks < 2; ++ks) {
            a1[mt][ks] = __builtin_bit_cast(bf16x8,
                *(const ushort8*)(wt1 + (mt * 16 + c) * 64 + ks * 32 + q * 8));
            a2[mt][ks] = __builtin_bit_cast(bf16x8,
                *(const ushort8*)(wt2 + (mt * 16 + c) * 64 + ks * 32 + q * 8));
        }
#pragma unroll
    for (int mt = 0; mt < 2; ++mt)
#pragma unroll
        for (int ks = 0; ks < 2; ++ks)
            a3[mt][ks] = __builtin_bit_cast(bf16x8,
                *(const ushort8*)(ht + (mt * 16 + c) * 64 + ks * 32 + q * 8));
    f32x4 b1v[4], b2v[4], hbv[2];
#pragma unroll
    for (int mt = 0; mt < 4; ++mt) {
        b1v[mt] = *(const f32x4*)(b1 + mt * 16 + q * 4);
        b2v[mt] = *(const f32x4*)(b2 + mt * 16 + q * 4);
    }
#pragma unroll
    for (int mt = 0; mt < 2; ++mt)
        hbv[mt] = *(const f32x4*)(hbp + mt * 16 + q * 4);

    const int ntiles = N_NODES / 16;
    for (int tile = gwave; tile < ntiles; tile += nwaves) {
        const int n0 = tile * 16;
        const unsigned short* xr = xbf + (size_t)(n0 + c) * 64;
        const float* ar = agg + (size_t)(n0 + c) * 64;

        bf16x8 hb[2];
#pragma unroll
        for (int ks = 0; ks < 2; ++ks) {
            const int o = ks * 32 + q * 8;
            const int b0 = o >> 2, b1i = b0 + 1;
            const int pb0 = (b0 & 3) * 16 + (b0 >> 2) * 4;
            const int pb1 = (b1i & 3) * 16 + (b1i >> 2) * 4;
            const u16x4 xa4 = *(const u16x4*)(xr + pb0);
            const u16x4 xb4 = *(const u16x4*)(xr + pb1);
            const f32x4 aa = *(const f32x4*)(ar + pb0);
            const f32x4 ab = *(const f32x4*)(ar + pb1);
            ushort8 u;
#pragma unroll
            for (int i = 0; i < 4; ++i) {
                u[i]     = f2bf(bf2f(xa4[i]) + aa[i]);
                u[4 + i] = f2bf(bf2f(xb4[i]) + ab[i]);
            }
            hb[ks] = __builtin_bit_cast(bf16x8, u);
        }

        f32x4 acc[4];
#pragma unroll
        for (int mt = 0; mt < 4; ++mt) {
            acc[mt] = __builtin_amdgcn_mfma_f32_16x16x32_bf16(
                a1[mt][0], hb[0], (f32x4){0.f, 0.f, 0.f, 0.f}, 0, 0, 0);
            acc[mt] = __builtin_amdgcn_mfma_f32_16x16x32_bf16(
                a1[mt][1], hb[1], acc[mt], 0, 0, 0);
        }

#pragma unroll
        for (int mt = 0; mt < 4; ++mt) {
            f32x4 t;
#pragma unroll
            for (int r = 0; r < 4; ++r) t[r] = fmaxf(acc[mt][r] + b1v[mt][r], 0.f);
            *(f32x4*)(L + c * LSTRIDE + mt * 16 + q * 4) = t;
        }
        asm volatile("s_waitcnt lgkmcnt(0)" ::: "memory");

        bf16x8 tb[2];
#pragma unroll
        for (int ks = 0; ks < 2; ++ks) {
            const f32x4 lo = *(const f32x4*)(L + c * LSTRIDE + ks * 32 + q * 8);
            const f32x4 hi = *(const f32x4*)(L + c * LSTRIDE + ks * 32 + q * 8 + 4);
            ushort8 u;
            u[0] = f2bf(lo[0]); u[1] = f2bf(lo[1]); u[2] = f2bf(lo[2]); u[3] = f2bf(lo[3]);
            u[4] = f2bf(hi[0]); u[5] = f2bf(hi[1]); u[6] = f2bf(hi[2]); u[7] = f2bf(hi[3]);
            tb[ks] = __builtin_bit_cast(bf16x8, u);
        }
        asm volatile("s_waitcnt lgkmcnt(0)" ::: "memory");

#pragma unroll
        for (int mt = 0; mt < 4; ++mt) {
            acc[mt] = __builtin_amdgcn_mfma_f32_16x16x32_bf16(
                a2[mt][0], tb[0], (f32x4){0.f, 0.f, 0.f, 0.f}, 0, 0, 0);
            acc[mt] = __builtin_amdgcn_mfma_f32_16x16x32_bf16(
                a2[mt][1], tb[1], acc[mt], 0, 0, 0);
        }

#pragma unroll
        for (int mt = 0; mt < 4; ++mt) {
            f32x4 t;
#pragma unroll
            for (int r = 0; r < 4; ++r) t[r] = fmaxf(acc[mt][r] + b2v[mt][r], 0.f);
            *(f32x4*)(L + c * LSTRIDE + mt * 16 + q * 4) = t;
        }
        asm volatile("s_waitcnt lgkmcnt(0)" ::: "memory");

        bf16x8 ub[2];
#pragma unroll
        for (int ks = 0; ks < 2; ++ks) {
            const f32x4 lo = *(const f32x4*)(L + c * LSTRIDE + ks * 32 + q * 8);
            const f32x4 hi = *(const f32x4*)(L + c * LSTRIDE + ks * 32 + q * 8 + 4);
            ushort8 u;
            u[0] = f2bf(lo[0]); u[1] = f2bf(lo[1]); u[2] = f2bf(lo[2]); u[3] = f2bf(lo[3]);
            u[4] = f2bf(hi[0]); u[5] = f2bf(hi[1]); u[6] = f2bf(hi[2]); u[7] = f2bf(hi[3]);
            ub[ks] = __builtin_bit_cast(bf16x8, u);
        }
        asm volatile("s_waitcnt lgkmcnt(0)" ::: "memory");

        f32x4 acc3[2];
#pragma unroll
        for (int mt = 0; mt < 2; ++mt) {
            acc3[mt] = __builtin_amdgcn_mfma_f32_16x16x32_bf16(
                a3[mt][0], ub[0], (f32x4){0.f, 0.f, 0.f, 0.f}, 0, 0, 0);
            acc3[mt] = __builtin_amdgcn_mfma_f32_16x16x32_bf16(
                a3[mt][1], ub[1], acc3[mt], 0, 0, 0);
        }

        float* outr = outp + (size_t)(n0 + c) * 32;
#pragma unroll
        for (int mt = 0; mt < 2; ++mt) {
            f32x4 u;
#pragma unroll
            for (int r = 0; r < 4; ++r) u[r] = acc3[mt][r] + hbv[mt][r];
            *(f32x4*)(outr + mt * 16 + q * 4) = u;
        }
    }
}

extern "C" void kernel_launch(void* const* d_in, const int* in_sizes, int n_in,
                              void* d_out, int out_size, void* d_ws, size_t ws_size,
                              hipStream_t stream) {
    const float* x     = (const float*)d_in[0];
    const float* ea    = (const float*)d_in[1];
    const int*   ei    = (const int*)  d_in[2];
    const float* c1lw  = (const float*)d_in[3];
    const float* c1lb  = (const float*)d_in[4];
    const float* c1w1  = (const float*)d_in[5];
    const float* c1b1  = (const float*)d_in[6];
    const float* c1w2  = (const float*)d_in[7];
    const float* c1b2  = (const float*)d_in[8];
    const float* c2lw  = (const float*)d_in[9];
    const float* c2lb  = (const float*)d_in[10];
    const float* c2w1  = (const float*)d_in[11];
    const float* c2b1  = (const float*)d_in[12];
    const float* c2w2  = (const float*)d_in[13];
    const float* c2b2  = (const float*)d_in[14];
    const float* hw    = (const float*)d_in[15];
    const float* hb    = (const float*)d_in[16];

    const int* srcp = ei;
    const int* dstp = ei + N_EDGES;

    float*          agg = (float*)d_ws;                                  // [N,64] f32
    unsigned short* xbf = (unsigned short*)(agg + (size_t)N_NODES * 64); // [N,64] bf16
    unsigned short* hbf = xbf + (size_t)N_NODES * 64;                    // [N,64] bf16
    int*   cnt  = (int*)(hbf + (size_t)N_NODES * 64);                    // [N]
    int*   offs = cnt + N_NODES;                                         // [N+1]
    int*   bsum = offs + (N_NODES + 1);                                  // [256]
    int*   bpre = bsum + 256;                                            // [256]
    size_t wtb_off = ((size_t)((char*)(bpre + 256) - (char*)d_ws) + 63) & ~(size_t)63;
    unsigned short* wtb = (unsigned short*)((char*)d_ws + wtb_off);      // [22528]
    unsigned short* lt1  = wtb;
    unsigned short* wt1a = wtb + 2048;
    unsigned short* wt1b = wtb + 6144;
    unsigned short* lt2  = wtb + 10240;
    unsigned short* wt2a = wtb + 12288;
    unsigned short* wt2b = wtb + 16384;
    unsigned short* ht   = wtb + 20480;
    int*   ssrc = (int*)(wtb + WTB_ELEMS);                               // [E]
    int*   rank = ssrc + N_EDGES;                                        // [E]
    size_t tail_off = ((size_t)((char*)(rank + N_EDGES) - (char*)d_ws) + 63) & ~(size_t)63;
    unsigned short* ea_s = (unsigned short*)((char*)d_ws + tail_off);    // [E,32] bf16
    int*            perm_tail = (int*)((char*)d_ws + tail_off);          // fallback [E]
    const bool primary = ws_size >= tail_off + (size_t)N_EDGES * 32 * sizeof(unsigned short) + 64;

    float* outp = (float*)d_out;
    const int SCAN_G = (N_NODES + 255) / 256;

    // CSR build + weight prep (shared by both paths)
    hipMemsetAsync(cnt, 0, N_NODES * sizeof(int), stream);
    hipLaunchKernelGGL(hist_rank_xbf, dim3(2048), dim3(256), 0, stream,
                       dstp, cnt, rank, x, xbf);
    hipLaunchKernelGGL(scan_p1, dim3(256),    dim3(256), 0, stream, cnt, bsum);
    hipLaunchKernelGGL(scan_p2, dim3(1),      dim3(256), 0, stream, bsum, bpre, offs);
    hipLaunchKernelGGL(scan_p3, dim3(SCAN_G), dim3(256), 0, stream, cnt, bpre, offs);
    hipLaunchKernelGGL(w_prep, dim3((WTB_ELEMS + 255) / 256), dim3(256), 0, stream,
                       c1lw, c1w1, c1w2, c2lw, c2w1, c2w2, hw, wtb);

    if (primary) {
        hipLaunchKernelGGL(csr_scatter_ea4, dim3((N_EDGES * 4 + 255) / 256), dim3(256),
                           0, stream, ea, srcp, dstp, rank, offs, ssrc, ea_s);
        hipLaunchKernelGGL(gine_gather_bf, dim3(4096), dim3(256), 0, stream,
                           xbf, ea_s, ssrc, offs, lt1, c1lb, agg);
        hipLaunchKernelGGL(gine_node_mfma, dim3(800), dim3(256), 0, stream,
                           x, agg, wt1a, c1b1, wt1b, c1b2, hbf);
        hipLaunchKernelGGL(gine_gather_bf, dim3(4096), dim3(256), 0, stream,
                           hbf, ea_s, ssrc, offs, lt2, c2lb, agg);
        hipLaunchKernelGGL(gine_node_head_mfma, dim3(800), dim3(256), 0, stream,
                           hbf, agg, wt2a, c2b1, wt2b, c2b2, ht, hb, outp);
    } else {
        // small-ws fallback: perm in tail, per-node gathers read ea randomly
        int* perm = perm_tail;
        hipLaunchKernelGGL(csr_scatter_perm_srcs, dim3(2048), dim3(256), 0, stream,
                           dstp, rank, offs, srcp, perm, ssrc);
        hipLaunchKernelGGL(gine_gather_fb, dim3(4096), dim3(256), 0, stream,
                           xbf, ea, perm, ssrc, offs, lt1, c1lb, agg);
        hipLaunchKernelGGL(gine_node_mfma, dim3(800), dim3(256), 0, stream,
                           x, agg, wt1a, c1b1, wt1b, c1b2, hbf);
        hipLaunchKernelGGL(gine_gather_fb, dim3(4096), dim3(256), 0, stream,
                           hbf, ea, perm, ssrc, offs, lt2, c2lb, agg);
        hipLaunchKernelGGL(gine_node_head_mfma, dim3(800), dim3(256), 0, stream,
                           hbf, agg, wt2a, c2b1, wt2b, c2b2, ht, hb, outp);
    }
}